// Round 2
// baseline (376.653 us; speedup 1.0000x reference)
//
#include <hip/hip_runtime.h>
#include <math.h>

// Problem constants
#define Bb 8
#define Kk 32
#define Hh 480
#define Ww 480
#define Nn 576
#define Dd 1024
#define CLSD 64
#define OUTD 256
#define INDIM 1093
#define BK 256           // B*K

typedef int v4i __attribute__((ext_vector_type(4)));

// SERIALIZED-PHASE design: one 1024-thread block per (b,k).
// The previous overlapped design ran the 236MB mask stream concurrently with
// pooling/GEMV1 that depend on L2-resident fm/W1 -> the stream cycles the 4MB
// XCD L2 ~7x per iteration (and the whole L3), escalating reuse reads to
// HBM. Serializing removes the contention at a cost of ~8us lost overlap.
//   Phase A: sample 576 ds pixels -> LDS bitmap (once, not per-wave)
//   Phase B: pooling, ALL 16 waves (4 row-groups x 4-wave row width)
//   Phase C: GEMV1 K<1024, ALL 16 waves (64-K slice each)
//   Phase D: full-res mask scan, ALL 16 waves, nt loads (single-use stream)
//   Phase E: geom finalize, cls-emb + geom GEMV1 tail, GeLU, LN, GEMV2.
// b = blockIdx%8: the 32 k-blocks of one b share an XCD L2 (fm slice 2.36MB).
__global__ __launch_bounds__(1024) void kF(const int* __restrict__ masks,
                                           const float* __restrict__ fm,
                                           const int* __restrict__ cids,
                                           const float* __restrict__ emb,
                                           const float* __restrict__ W1,
                                           const float* __restrict__ b1,
                                           const float* __restrict__ lg,
                                           const float* __restrict__ lb,
                                           const float* __restrict__ W2,
                                           const float* __restrict__ b2,
                                           float* __restrict__ out) {
  const int b    = blockIdx.x & 7;
  const int k    = blockIdx.x >> 3;
  const int bk   = b * Kk + k;
  const int t    = threadIdx.x;
  const int lane = t & 63;
  const int w    = t >> 6;          // wave id 0..15

  __shared__ float  partial[16 * 256]; // GEMV partials / pooling scratch (16 KB)
  __shared__ float4 x4s[256];          // pooled x staging (4 KB)
  __shared__ float  hrow[256];
  __shared__ float  red_s[4], red_q[4];
  __shared__ float  gmeta[8];
  __shared__ int    gstat[16][7];      // per-wave scan stats
  __shared__ unsigned char m576[576];  // downsampled-mask bitmap
  __shared__ int    nact;

  const int* mbase = masks + (size_t)bk * (Hh * Ww);

  // ---------------- Phase A: downsample sampling -> bitmap ----------------
  if (t == 0) nact = 0;
  if (t < 576) {                      // waves 0..8 full, 9..15 skip
    int a = t / 24, c = t - a * 24;
    int mv = mbase[(a * 20) * Ww + c * 20];
    m576[t] = (mv > 0);
    unsigned long long bal = __ballot(mv > 0);
    if (lane == 0) atomicAdd(&nact, __popcll(bal));
  }
  __syncthreads();
  const int na = nact;

  // ---------------- Phase B: pooling, all 16 waves ----------------
  // group = t>>8 (4 waves each) handles rows n == grp (mod 4), full 1024-col
  // width (each wave: 64 float4 cols). Branch on m576[n] is wave-uniform.
  {
    const int grp  = t >> 8;          // 0..3
    const int colf = t & 255;         // float4 col index
    const float4* fmp = (const float4*)fm + (size_t)b * Nn * (Dd / 4);
    float ax = 0.f, ay = 0.f, az = 0.f, aw = 0.f;
    for (int n = grp; n < Nn; n += 4) {
      if (m576[n]) {
        float4 f = fmp[n * (Dd / 4) + colf];
        ax += f.x; ay += f.y; az += f.z; aw += f.w;
      }
    }
    float4* pools = (float4*)partial;   // alias scratch (4*256 float4 = 16 KB)
    float4 p; p.x = ax; p.y = ay; p.z = az; p.w = aw;
    pools[grp * 256 + colf] = p;
  }
  __syncthreads();
  if (t < 256) {
    const float4* pools = (const float4*)partial;
    float4 p0 = pools[t], p1 = pools[256 + t], p2 = pools[512 + t], p3 = pools[768 + t];
    float inv = 1.0f / fmaxf((float)na, 1e-6f);
    float4 xp;
    xp.x = (p0.x + p1.x + p2.x + p3.x) * inv;
    xp.y = (p0.y + p1.y + p2.y + p3.y) * inv;
    xp.z = (p0.z + p1.z + p2.z + p3.z) * inv;
    xp.w = (p0.w + p1.w + p2.w + p3.w) * inv;
    x4s[t] = xp;
  }
  __syncthreads();

  // ---------------- Phase C: GEMV1 over K<1024, all 16 waves ----------------
  // wave w owns K-slice [64w, 64w+64); lane owns output cols 4*lane..4*lane+3
  {
    float4 acc = {0.f, 0.f, 0.f, 0.f};
    const float* W1b = W1 + (size_t)(w * 64) * OUTD + 4 * lane;
#pragma unroll 4
    for (int g = 0; g < 16; g++) {
      float4 xv = x4s[w * 16 + g];    // wave-uniform LDS broadcast
      const float* xs = (const float*)&xv;
#pragma unroll
      for (int u = 0; u < 4; u++) {
        float4 w4 = *(const float4*)(W1b + (size_t)(4 * g + u) * OUTD);
        acc.x = fmaf(xs[u], w4.x, acc.x);
        acc.y = fmaf(xs[u], w4.y, acc.y);
        acc.z = fmaf(xs[u], w4.z, acc.z);
        acc.w = fmaf(xs[u], w4.w, acc.w);
      }
    }
    *(float4*)(partial + w * 256 + 4 * lane) = acc;
  }
  // no barrier needed yet: partial re-read only after the scan's barrier

  // ---------------- Phase D: full-res scan, all 16 waves, nt loads --------
  {
    int area = 0, sumx = 0, sumy = 0;
    int minx = Ww, maxx = -1, miny = Hh, maxy = -1;
    const v4i* mp = (const v4i*)mbase;

#define SCAN_BODY(qq)                                                   \
    {                                                                   \
      int q = (qq);                                                     \
      v4i v = __builtin_nontemporal_load(mp + q);                       \
      int h   = q / 120;                                                \
      int rem = q - h * 120;                                            \
      int w0  = rem * 4;                                                \
      int m0 = v.x > 0, m1 = v.y > 0, m2 = v.z > 0, m3 = v.w > 0;       \
      int c = m0 + m1 + m2 + m3;                                        \
      area += c;                                                        \
      sumy += h * c;                                                    \
      sumx += w0 * c + m1 + 2 * m2 + 3 * m3;                            \
      if (c) {                                                          \
        miny = min(miny, h);                                            \
        maxy = max(maxy, h);                                            \
        int lo = m0 ? w0 : (m1 ? w0 + 1 : (m2 ? w0 + 2 : w0 + 3));      \
        int hi = m3 ? w0 + 3 : (m2 ? w0 + 2 : (m1 ? w0 + 1 : w0));      \
        minx = min(minx, lo);                                           \
        maxx = max(maxx, hi);                                           \
      }                                                                 \
    }

#pragma unroll 4
    for (int i = 0; i < 56; i++) SCAN_BODY(t + i * 1024)
    if (t < 256) SCAN_BODY(57344 + t)
#undef SCAN_BODY

    for (int off = 32; off; off >>= 1) {
      area += __shfl_down(area, off);
      sumx += __shfl_down(sumx, off);
      sumy += __shfl_down(sumy, off);
      minx = min(minx, __shfl_down(minx, off));
      maxx = max(maxx, __shfl_down(maxx, off));
      miny = min(miny, __shfl_down(miny, off));
      maxy = max(maxy, __shfl_down(maxy, off));
    }
    if (lane == 0) {
      gstat[w][0] = area; gstat[w][1] = sumx; gstat[w][2] = sumy;
      gstat[w][3] = minx; gstat[w][4] = maxx;
      gstat[w][5] = miny; gstat[w][6] = maxy;
    }
  }
  __syncthreads();

  // ---------------- Phase E: epilogue ----------------
  if (t == 0) {
    int area = 0, sumx = 0, sumy = 0;
    int minx = Ww, maxx = -1, miny = Hh, maxy = -1;
#pragma unroll
    for (int i = 0; i < 16; i++) {
      area += gstat[i][0]; sumx += gstat[i][1]; sumy += gstat[i][2];
      minx = min(minx, gstat[i][3]); maxx = max(maxx, gstat[i][4]);
      miny = min(miny, gstat[i][5]); maxy = max(maxy, gstat[i][6]);
    }
    float areaf = (float)area;
    float safe  = fmaxf(areaf, 1.0f);
    float cx = ((float)sumx / safe) * (1.0f / Ww);
    float cy = ((float)sumy / safe) * (1.0f / Hh);
    float an = areaf * (1.0f / (Hh * Ww));
    float bw = (float)(maxx - minx + 1) * (1.0f / Ww);
    float bh = (float)(maxy - miny + 1) * (1.0f / Hh);
    if (area < 1) { cx = 0.f; cy = 0.f; an = 0.f; bw = 0.f; bh = 0.f; }
    gmeta[0] = cx; gmeta[1] = cy; gmeta[2] = an; gmeta[3] = bw; gmeta[4] = bh;
  }
  __syncthreads();

  // combine + cls/geom GEMV1 tail + GeLU  (threads 0..255)
  float hv = 0.f;
  if (t < 256) {
    hv = b1[t];
#pragma unroll
    for (int ww = 0; ww < 16; ww++) hv += partial[ww * 256 + t];
    const float* et = emb + (size_t)cids[bk] * CLSD;
#pragma unroll 8
    for (int i = 0; i < CLSD; i++)
      hv = fmaf(et[i], W1[(size_t)(Dd + i) * OUTD + t], hv);
#pragma unroll
    for (int jj = 0; jj < 5; jj++)
      hv = fmaf(gmeta[jj], W1[(size_t)(Dd + CLSD + jj) * OUTD + t], hv);
    hv = 0.5f * hv * (1.0f + erff(hv * 0.7071067811865475f));
  }
  {
    float s = hv, q = hv * hv;
    for (int off = 32; off; off >>= 1) {
      s += __shfl_down(s, off);
      q += __shfl_down(q, off);
    }
    if (lane == 0 && w < 4) { red_s[w] = s; red_q[w] = q; }
  }
  __syncthreads();
  if (t < 256) {
    float s = red_s[0] + red_s[1] + red_s[2] + red_s[3];
    float q = red_q[0] + red_q[1] + red_q[2] + red_q[3];
    float mu  = s * (1.0f / OUTD);
    float var = q * (1.0f / OUTD) - mu * mu;
    float ist = 1.0f / sqrtf(var + 1e-5f);
    hrow[t] = (hv - mu) * ist * lg[t] + lb[t];
  }
  __syncthreads();

  // GEMV2: 16-way wave K-split, float4 W2 loads
  {
    float4 acc = {0.f, 0.f, 0.f, 0.f};
#pragma unroll
    for (int i = 0; i < 4; i++) {
      float4 h4 = ((const float4*)hrow)[w * 4 + i];
      const float* hs = (const float*)&h4;
#pragma unroll
      for (int u = 0; u < 4; u++) {
        int kk = w * 16 + i * 4 + u;
        float4 w4 = *(const float4*)(W2 + (size_t)kk * OUTD + 4 * lane);
        acc.x = fmaf(hs[u], w4.x, acc.x);
        acc.y = fmaf(hs[u], w4.y, acc.y);
        acc.z = fmaf(hs[u], w4.z, acc.z);
        acc.w = fmaf(hs[u], w4.w, acc.w);
      }
    }
    *(float4*)(partial + w * 256 + 4 * lane) = acc;
  }
  __syncthreads();

  if (t < 256) {
    float c = b2[t];
#pragma unroll
    for (int ww = 0; ww < 16; ww++) c += partial[ww * 256 + t];
    __builtin_nontemporal_store(c, out + (size_t)bk * OUTD + t);
  }
}

extern "C" void kernel_launch(void* const* d_in, const int* in_sizes, int n_in,
                              void* d_out, int out_size, void* d_ws, size_t ws_size,
                              hipStream_t stream) {
  const float* fm    = (const float*)d_in[0];
  const int*   masks = (const int*)d_in[1];
  const int*   cids  = (const int*)d_in[2];
  const float* emb   = (const float*)d_in[3];
  const float* W1    = (const float*)d_in[4];
  const float* b1    = (const float*)d_in[5];
  const float* lg    = (const float*)d_in[6];
  const float* lb    = (const float*)d_in[7];
  const float* W2    = (const float*)d_in[8];
  const float* b2    = (const float*)d_in[9];
  float* out = (float*)d_out;

  hipLaunchKernelGGL(kF, dim3(BK), dim3(1024), 0, stream, masks, fm, cids, emb,
                     W1, b1, lg, lb, W2, b2, out);
}